// Round 1
// baseline (2984.211 us; speedup 1.0000x reference)
//
#include <hip/hip_runtime.h>
#include <hip/hip_bf16.h>
#include <math.h>

#define S_LEN 4096
#define EMB   1024
#define NHEAD 16
#define HDIM  64

// ---------------------------------------------------------------------------
// Tiled fp32 GEMM: C[M,N] = A[M,K] @ B[K,N] + bias[N]
// 64x64 tile, 256 threads, each thread computes 4x4. BK=16.
// M,N multiples of 64; K multiple of 16 (true for all our shapes).
// ---------------------------------------------------------------------------
__global__ __launch_bounds__(256) void gemm_bias(
    const float* __restrict__ A, const float* __restrict__ B,
    const float* __restrict__ bias, float* __restrict__ C,
    int M, int N, int K)
{
    const int BM = 64, BN = 64, BK = 16;
    __shared__ float As[BK][BM + 4];   // As[k][m]; +4 keeps 16B row alignment
    __shared__ float Bs[BK][BN + 4];   // Bs[k][n]

    const int tx = threadIdx.x & 15;       // 0..15 -> N direction
    const int ty = threadIdx.x >> 4;       // 0..15 -> M direction
    const int row0 = blockIdx.y * BM;
    const int col0 = blockIdx.x * BN;

    float acc[4][4];
#pragma unroll
    for (int i = 0; i < 4; ++i)
#pragma unroll
        for (int j = 0; j < 4; ++j) acc[i][j] = 0.f;

    for (int k0 = 0; k0 < K; k0 += BK) {
        // Load A tile (64 rows x 16 k) transposed into As[k][m]
#pragma unroll
        for (int i = threadIdx.x; i < BM * BK; i += 256) {
            int r = i >> 4;          // 0..63 (m)
            int c = i & 15;          // 0..15 (k)
            As[c][r] = A[(size_t)(row0 + r) * K + k0 + c];
        }
        // Load B tile (16 k x 64 n)
#pragma unroll
        for (int i = threadIdx.x; i < BK * BN; i += 256) {
            int r = i >> 6;          // 0..15 (k)
            int c = i & 63;          // 0..63 (n)
            Bs[r][c] = B[(size_t)(k0 + r) * N + col0 + c];
        }
        __syncthreads();

#pragma unroll
        for (int kk = 0; kk < BK; ++kk) {
            float a[4], b[4];
#pragma unroll
            for (int i = 0; i < 4; ++i) a[i] = As[kk][ty * 4 + i];
#pragma unroll
            for (int j = 0; j < 4; ++j) b[j] = Bs[kk][tx * 4 + j];
#pragma unroll
            for (int i = 0; i < 4; ++i)
#pragma unroll
                for (int j = 0; j < 4; ++j)
                    acc[i][j] = fmaf(a[i], b[j], acc[i][j]);
        }
        __syncthreads();
    }

#pragma unroll
    for (int i = 0; i < 4; ++i) {
        int r = row0 + ty * 4 + i;
#pragma unroll
        for (int j = 0; j < 4; ++j) {
            int c = col0 + tx * 4 + j;
            C[(size_t)r * N + c] = acc[i][j] + bias[c];
        }
    }
}

// ---------------------------------------------------------------------------
// Causal flash attention, fp32. One thread per query row.
// qkv layout: [S, 3*EMB] = [q | k | v], head h occupies cols h*64..h*64+63.
// No 1/sqrt(D) scale (faithful to reference). Online softmax.
// res layout: [S, EMB] with res[s, h*64+d].
// ---------------------------------------------------------------------------
__global__ __launch_bounds__(256) void flash_attn(
    const float* __restrict__ qkv, float* __restrict__ res)
{
    __shared__ float Ks[64][HDIM];   // 16 KB
    __shared__ float Vs[64][HDIM];   // 16 KB

    const int h = blockIdx.y;
    const int s = blockIdx.x * 256 + threadIdx.x;   // this thread's query row
    const int smax = blockIdx.x * 256 + 255;        // max row in this block

    // load q row into registers
    const float* qrow = qkv + (size_t)s * (3 * EMB) + h * HDIM;
    float q[HDIM];
#pragma unroll
    for (int d = 0; d < HDIM; ++d) q[d] = qrow[d];

    float m = -INFINITY;
    float l = 0.f;
    float o[HDIM];
#pragma unroll
    for (int d = 0; d < HDIM; ++d) o[d] = 0.f;

    for (int kb = 0; kb <= smax; kb += 64) {
        __syncthreads();   // protect LDS from previous iteration's readers
        // cooperative load of K and V blocks: 64 keys x 64 dims each
        for (int i = threadIdx.x; i < 64 * HDIM; i += 256) {
            int kk = i >> 6;        // key within block
            int d  = i & 63;        // dim
            size_t base = (size_t)(kb + kk) * (3 * EMB) + h * HDIM + d;
            Ks[kk][d] = qkv[base + EMB];
            Vs[kk][d] = qkv[base + 2 * EMB];
        }
        __syncthreads();

        const int jmax = min(63, s - kb);   // inclusive; negative -> skip
        for (int j = 0; j <= jmax; ++j) {
            float sc = 0.f;
#pragma unroll
            for (int d = 0; d < HDIM; ++d)
                sc = fmaf(q[d], Ks[j][d], sc);   // broadcast LDS reads

            float p;
            if (sc > m) {
                float scale = __expf(m - sc);    // m=-inf -> scale=0 (first hit)
                l *= scale;
#pragma unroll
                for (int d = 0; d < HDIM; ++d) o[d] *= scale;
                m = sc;
                p = 1.0f;
            } else {
                p = __expf(sc - m);
            }
            l += p;
#pragma unroll
            for (int d = 0; d < HDIM; ++d)
                o[d] = fmaf(p, Vs[j][d], o[d]);
        }
    }

    const float inv = 1.0f / l;
    float* orow = res + (size_t)s * EMB + h * HDIM;
#pragma unroll
    for (int d = 0; d < HDIM; ++d) orow[d] = o[d] * inv;
}

// ---------------------------------------------------------------------------
// launch
// ---------------------------------------------------------------------------
extern "C" void kernel_launch(void* const* d_in, const int* in_sizes, int n_in,
                              void* d_out, int out_size, void* d_ws, size_t ws_size,
                              hipStream_t stream)
{
    const float* x    = (const float*)d_in[0];
    // d_in[1] = causal mask (bool) — structure is known, ignored.
    const float* Wqkv = (const float*)d_in[2];
    const float* bqkv = (const float*)d_in[3];
    const float* Wp   = (const float*)d_in[4];
    const float* bp   = (const float*)d_in[5];
    float* out = (float*)d_out;

    float* qkv = (float*)d_ws;                          // [4096, 3072] = 50.3 MB
    float* res = qkv + (size_t)S_LEN * 3 * EMB;         // [4096, 1024] = 16.8 MB

    dim3 blk(256);

    // qkv = x @ Wqkv + bqkv   (M=4096, N=3072, K=1024)
    gemm_bias<<<dim3(3 * EMB / 64, S_LEN / 64), blk, 0, stream>>>(
        x, Wqkv, bqkv, qkv, S_LEN, 3 * EMB, EMB);

    // attention per head, causal, online softmax
    flash_attn<<<dim3(S_LEN / 256, NHEAD), blk, 0, stream>>>(qkv, res);

    // out = res @ Wp + bp     (M=4096, N=1024, K=1024)
    gemm_bias<<<dim3(EMB / 64, S_LEN / 64), blk, 0, stream>>>(
        res, Wp, bp, out, S_LEN, EMB, EMB);
}

// Round 2
// 1037.613 us; speedup vs baseline: 2.8760x; 2.8760x over previous
//
#include <hip/hip_runtime.h>
#include <hip/hip_bf16.h>
#include <math.h>

#define S_LEN 4096
#define EMB   1024
#define NHEAD 16
#define HDIM  64

typedef __attribute__((ext_vector_type(8))) short short8;
typedef __attribute__((ext_vector_type(4))) float float4_t;

__device__ __forceinline__ unsigned short f2bf_rne(float f) {
    union { float f; unsigned int u; } v; v.f = f;
    unsigned int u = v.u;
    return (unsigned short)((u + 0x7FFF + ((u >> 16) & 1)) >> 16);
}
__device__ __forceinline__ float bfbits2f(unsigned short b) {
    union { unsigned int u; float f; } v; v.u = ((unsigned int)b) << 16;
    return v.f;
}

// ---------------------------------------------------------------------------
// Tiled fp32 GEMM: C[M,N] = A[M,K] @ B[K,N] + bias[N]   (unchanged, round 1)
// ---------------------------------------------------------------------------
__global__ __launch_bounds__(256) void gemm_bias(
    const float* __restrict__ A, const float* __restrict__ B,
    const float* __restrict__ bias, float* __restrict__ C,
    int M, int N, int K)
{
    const int BM = 64, BN = 64, BK = 16;
    __shared__ float As[BK][BM + 4];
    __shared__ float Bs[BK][BN + 4];

    const int tx = threadIdx.x & 15;
    const int ty = threadIdx.x >> 4;
    const int row0 = blockIdx.y * BM;
    const int col0 = blockIdx.x * BN;

    float acc[4][4];
#pragma unroll
    for (int i = 0; i < 4; ++i)
#pragma unroll
        for (int j = 0; j < 4; ++j) acc[i][j] = 0.f;

    for (int k0 = 0; k0 < K; k0 += BK) {
#pragma unroll
        for (int i = threadIdx.x; i < BM * BK; i += 256) {
            int r = i >> 4, c = i & 15;
            As[c][r] = A[(size_t)(row0 + r) * K + k0 + c];
        }
#pragma unroll
        for (int i = threadIdx.x; i < BK * BN; i += 256) {
            int r = i >> 6, c = i & 63;
            Bs[r][c] = B[(size_t)(k0 + r) * N + col0 + c];
        }
        __syncthreads();
#pragma unroll
        for (int kk = 0; kk < BK; ++kk) {
            float a[4], b[4];
#pragma unroll
            for (int i = 0; i < 4; ++i) a[i] = As[kk][ty * 4 + i];
#pragma unroll
            for (int j = 0; j < 4; ++j) b[j] = Bs[kk][tx * 4 + j];
#pragma unroll
            for (int i = 0; i < 4; ++i)
#pragma unroll
                for (int j = 0; j < 4; ++j)
                    acc[i][j] = fmaf(a[i], b[j], acc[i][j]);
        }
        __syncthreads();
    }
#pragma unroll
    for (int i = 0; i < 4; ++i) {
        int r = row0 + ty * 4 + i;
#pragma unroll
        for (int j = 0; j < 4; ++j) {
            int c = col0 + tx * 4 + j;
            C[(size_t)r * N + c] = acc[i][j] + bias[c];
        }
    }
}

// ---------------------------------------------------------------------------
// MFMA causal flash attention.
// Block: 256 threads = 4 waves; each wave owns 16 query rows; block = 64 rows
// of one head. Key tiles of 64 staged in LDS as bf16 (K split hi/lo for
// fp32-accurate logits; V plain bf16, stored transposed [d][key]).
// mfma_f32_16x16x32_bf16: A[m=lane&15][k=quad*8+j]; B[k=quad*8+j][n=lane&15];
// C/D[row=quad*4+reg][col=lane&15]  (verified layouts, m89/m91).
// ---------------------------------------------------------------------------
__global__ __launch_bounds__(256) void flash_attn_mfma(
    const float* __restrict__ qkv, float* __restrict__ res)
{
    // rows padded to 72 bf16 (144 B = 9*16: keeps b128 alignment, 2-way banks)
    __shared__ __align__(16) unsigned short KsHi[64][72];
    __shared__ __align__(16) unsigned short KsLo[64][72];
    __shared__ __align__(16) unsigned short Vt[64][72];      // [d][key]
    __shared__ __align__(16) unsigned short Pb[4][16][72];   // per-wave P

    const int h    = blockIdx.y;
    const int qt   = gridDim.x - 1 - blockIdx.x;   // heaviest tiles first
    const int bq0  = qt * 64;
    const int tid  = threadIdx.x;
    const int wave = tid >> 6;
    const int lane = tid & 63;
    const int l16  = lane & 15;
    const int quad = lane >> 4;
    const int q0   = bq0 + wave * 16;              // this wave's first q row

    // ---- load Q fragments (rows q0..q0+15), split hi/lo --------------------
    const float* qp = qkv + (size_t)(q0 + l16) * (3 * EMB) + h * HDIM + quad * 8;
    short8 qhi0, qlo0, qhi1, qlo1;
#pragma unroll
    for (int j = 0; j < 8; ++j) {
        float f = qp[j];
        unsigned short hb = f2bf_rne(f);
        qhi0[j] = (short)hb;
        qlo0[j] = (short)f2bf_rne(f - bfbits2f(hb));
        float g = qp[32 + j];
        unsigned short hb2 = f2bf_rne(g);
        qhi1[j] = (short)hb2;
        qlo1[j] = (short)f2bf_rne(g - bfbits2f(hb2));
    }

    float4_t o[4];
    float m[4], l[4];
#pragma unroll
    for (int ct = 0; ct < 4; ++ct) o[ct] = (float4_t){0.f, 0.f, 0.f, 0.f};
#pragma unroll
    for (int r = 0; r < 4; ++r) { m[r] = -INFINITY; l[r] = 0.f; }

    for (int kb = 0; kb <= bq0 + 63; kb += 64) {
        __syncthreads();
        // ---- stage K (hi/lo) and V^T tiles ---------------------------------
#pragma unroll
        for (int p = 0; p < 2; ++p) {
            int key = p * 32 + (tid >> 3);
            int d8  = (tid & 7) * 8;
            const float* kp = qkv + (size_t)(kb + key) * (3 * EMB) + EMB + h * HDIM + d8;
            const float* vp = kp + EMB;
            short8 khi, klo;
#pragma unroll
            for (int j = 0; j < 8; ++j) {
                float f = kp[j];
                unsigned short hb = f2bf_rne(f);
                khi[j] = (short)hb;
                klo[j] = (short)f2bf_rne(f - bfbits2f(hb));
                Vt[d8 + j][key] = f2bf_rne(vp[j]);
            }
            *(short8*)&KsHi[key][d8] = khi;
            *(short8*)&KsLo[key][d8] = klo;
        }
        __syncthreads();

        if (kb > q0 + 15) continue;   // wave-uniform skip (barriers above stay)

        // ---- S = Q K^T : 4 n-tiles of 16 keys, 3-term hi/lo split ----------
        float4_t s[4];
#pragma unroll
        for (int t = 0; t < 4; ++t) {
            s[t] = (float4_t){0.f, 0.f, 0.f, 0.f};
            const int kr = t * 16 + l16;
            short8 bh0 = *(const short8*)&KsHi[kr][quad * 8];
            short8 bh1 = *(const short8*)&KsHi[kr][32 + quad * 8];
            short8 bl0 = *(const short8*)&KsLo[kr][quad * 8];
            short8 bl1 = *(const short8*)&KsLo[kr][32 + quad * 8];
            s[t] = __builtin_amdgcn_mfma_f32_16x16x32_bf16(qhi0, bh0, s[t], 0, 0, 0);
            s[t] = __builtin_amdgcn_mfma_f32_16x16x32_bf16(qhi1, bh1, s[t], 0, 0, 0);
            s[t] = __builtin_amdgcn_mfma_f32_16x16x32_bf16(qlo0, bh0, s[t], 0, 0, 0);
            s[t] = __builtin_amdgcn_mfma_f32_16x16x32_bf16(qlo1, bh1, s[t], 0, 0, 0);
            s[t] = __builtin_amdgcn_mfma_f32_16x16x32_bf16(qhi0, bl0, s[t], 0, 0, 0);
            s[t] = __builtin_amdgcn_mfma_f32_16x16x32_bf16(qhi1, bl1, s[t], 0, 0, 0);
        }

        // ---- causal mask + online softmax ----------------------------------
#pragma unroll
        for (int t = 0; t < 4; ++t) {
            const int c = kb + t * 16 + l16;
#pragma unroll
            for (int r = 0; r < 4; ++r) {
                const int row = q0 + quad * 4 + r;
                if (c > row) s[t][r] = -INFINITY;
            }
        }
#pragma unroll
        for (int r = 0; r < 4; ++r) {
            float mx = fmaxf(fmaxf(s[0][r], s[1][r]), fmaxf(s[2][r], s[3][r]));
#pragma unroll
            for (int off = 1; off < 16; off <<= 1)
                mx = fmaxf(mx, __shfl_xor(mx, off));
            float mnew  = fmaxf(m[r], mx);
            float alpha = __expf(m[r] - mnew);       // first iter: exp(-inf)=0
            float rowsum = 0.f;
#pragma unroll
            for (int t = 0; t < 4; ++t) {
                float p = __expf(s[t][r] - mnew);    // masked: exp(-inf)=0
                rowsum += p;
                Pb[wave][quad * 4 + r][t * 16 + l16] = f2bf_rne(p);
            }
#pragma unroll
            for (int off = 1; off < 16; off <<= 1)
                rowsum += __shfl_xor(rowsum, off);
            l[r] = l[r] * alpha + rowsum;
            m[r] = mnew;
#pragma unroll
            for (int ct = 0; ct < 4; ++ct) o[ct][r] *= alpha;
        }

        // ---- O += P V : P via per-wave LDS relayout (same-wave, in-order) --
        short8 pa0 = *(const short8*)&Pb[wave][l16][quad * 8];
        short8 pa1 = *(const short8*)&Pb[wave][l16][32 + quad * 8];
#pragma unroll
        for (int ct = 0; ct < 4; ++ct) {
            const int dr = ct * 16 + l16;
            short8 vb0 = *(const short8*)&Vt[dr][quad * 8];
            short8 vb1 = *(const short8*)&Vt[dr][32 + quad * 8];
            o[ct] = __builtin_amdgcn_mfma_f32_16x16x32_bf16(pa0, vb0, o[ct], 0, 0, 0);
            o[ct] = __builtin_amdgcn_mfma_f32_16x16x32_bf16(pa1, vb1, o[ct], 0, 0, 0);
        }
    }

    // ---- epilogue: O / l -> res ------------------------------------------
    float inv[4];
#pragma unroll
    for (int r = 0; r < 4; ++r) inv[r] = 1.0f / l[r];
#pragma unroll
    for (int ct = 0; ct < 4; ++ct) {
#pragma unroll
        for (int r = 0; r < 4; ++r) {
            const int row = q0 + quad * 4 + r;
            res[(size_t)row * EMB + h * HDIM + ct * 16 + l16] = o[ct][r] * inv[r];
        }
    }
}

// ---------------------------------------------------------------------------
// launch
// ---------------------------------------------------------------------------
extern "C" void kernel_launch(void* const* d_in, const int* in_sizes, int n_in,
                              void* d_out, int out_size, void* d_ws, size_t ws_size,
                              hipStream_t stream)
{
    const float* x    = (const float*)d_in[0];
    const float* Wqkv = (const float*)d_in[2];
    const float* bqkv = (const float*)d_in[3];
    const float* Wp   = (const float*)d_in[4];
    const float* bp   = (const float*)d_in[5];
    float* out = (float*)d_out;

    float* qkv = (float*)d_ws;                      // [4096, 3072]
    float* res = qkv + (size_t)S_LEN * 3 * EMB;     // [4096, 1024]

    dim3 blk(256);

    gemm_bias<<<dim3(3 * EMB / 64, S_LEN / 64), blk, 0, stream>>>(
        x, Wqkv, bqkv, qkv, S_LEN, 3 * EMB, EMB);

    flash_attn_mfma<<<dim3(S_LEN / 64, NHEAD), blk, 0, stream>>>(qkv, res);

    gemm_bias<<<dim3(EMB / 64, S_LEN / 64), blk, 0, stream>>>(
        res, Wp, bp, out, S_LEN, EMB, EMB);
}

// Round 3
// 603.748 us; speedup vs baseline: 4.9428x; 1.7186x over previous
//
#include <hip/hip_runtime.h>
#include <hip/hip_bf16.h>
#include <math.h>

#define S_LEN 4096
#define EMB   1024
#define NHEAD 16
#define HDIM  64

typedef __attribute__((ext_vector_type(8))) short short8;
typedef __attribute__((ext_vector_type(4))) short short4_t;
typedef __attribute__((ext_vector_type(4))) float float4_t;
typedef unsigned short ushort_t;

#define GLOBAL_AS(p) ((const __attribute__((address_space(1))) void*)(p))
#define LDS_AS(p)    ((__attribute__((address_space(3))) void*)(p))

__device__ __forceinline__ unsigned short f2bf_rne(float f) {
    union { float f; unsigned int u; } v; v.f = f;
    unsigned int u = v.u;
    return (unsigned short)((u + 0x7FFF + ((u >> 16) & 1)) >> 16);
}
__device__ __forceinline__ float bfbits2f(unsigned short b) {
    union { unsigned int u; float f; } v; v.u = ((unsigned int)b) << 16;
    return v.f;
}

// ---------------------------------------------------------------------------
// split fp32 -> bf16 hi/lo planes (row-major, same layout)
// ---------------------------------------------------------------------------
__global__ __launch_bounds__(256) void split_x(
    const float* __restrict__ in, ushort_t* __restrict__ oh, ushort_t* __restrict__ ol)
{
    const int i = blockIdx.x * 256 + threadIdx.x;
    const float4_t v = ((const float4_t*)in)[i];
    short4_t h, l;
#pragma unroll
    for (int j = 0; j < 4; ++j) {
        unsigned short hb = f2bf_rne(v[j]);
        h[j] = (short)hb;
        l[j] = (short)f2bf_rne(v[j] - bfbits2f(hb));
    }
    ((short4_t*)oh)[i] = h;
    ((short4_t*)ol)[i] = l;
}

// ---------------------------------------------------------------------------
// transpose fp32 [R,C] -> bf16 [C,R] (hi, and lo if SPLIT)
// ---------------------------------------------------------------------------
template<bool SPLIT>
__global__ __launch_bounds__(256) void transpose_split(
    const float* __restrict__ in, ushort_t* __restrict__ oh, ushort_t* __restrict__ ol,
    int R, int C)
{
    __shared__ float t[64][65];
    const int r0 = blockIdx.y * 64, c0 = blockIdx.x * 64;
    for (int i = threadIdx.x; i < 64 * 64; i += 256) {
        int r = i >> 6, c = i & 63;
        t[r][c] = in[(size_t)(r0 + r) * C + c0 + c];
    }
    __syncthreads();
    for (int i = threadIdx.x; i < 64 * 64; i += 256) {
        int c = i >> 6, r = i & 63;
        float f = t[r][c];
        unsigned short hb = f2bf_rne(f);
        oh[(size_t)(c0 + c) * R + r0 + r] = hb;
        if constexpr (SPLIT)
            ol[(size_t)(c0 + c) * R + r0 + r] = f2bf_rne(f - bfbits2f(hb));
    }
}

// ---------------------------------------------------------------------------
// MFMA GEMM, m97 structure: 128x128 tile, BK=32, global_load_lds width 16.
// A [M,K] row-major bf16 (hi + optional lo); B^T [N,K] row-major bf16.
// SPLIT: acc = Ahi*Bhi + Ahi*Blo + Alo*Bhi (fp32-accurate product).
// EPI 0: C fp32 = acc + bias.   EPI 1 (QKV): cols<2048 -> qk hi/lo planes
// [4096,2048]; cols>=2048 -> v bf16 [4096,1024].
// ---------------------------------------------------------------------------
template<bool SPLIT, int EPI>
__global__ __launch_bounds__(256) void gemm_mfma(
    const ushort_t* __restrict__ Ag, const ushort_t* __restrict__ Alg,
    const ushort_t* __restrict__ Bg, const ushort_t* __restrict__ Blg,
    const float* __restrict__ bias,
    float* __restrict__ C,
    ushort_t* __restrict__ qh, ushort_t* __restrict__ ql, ushort_t* __restrict__ vb,
    int M, int N, int K)
{
    constexpr int BK = 32;
    __shared__ ushort_t Ah[128 * BK];
    __shared__ ushort_t Bh[128 * BK];
    __shared__ ushort_t Al[SPLIT ? 128 * BK : 8];
    __shared__ ushort_t Bl[SPLIT ? 128 * BK : 8];

    const int tid = threadIdx.x;
    const int wave = tid >> 6, lane = tid & 63;
    const int l16 = lane & 15, quad = lane >> 4;
    const int wr = wave >> 1, wc = wave & 1;
    const int row0 = blockIdx.y * 128, col0 = blockIdx.x * 128;
    const int lrow = lane >> 2, lc8 = (lane & 3) * 8;

    float4_t acc[4][4];
#pragma unroll
    for (int i = 0; i < 4; ++i)
#pragma unroll
        for (int j = 0; j < 4; ++j) acc[i][j] = (float4_t){0.f, 0.f, 0.f, 0.f};

    for (int k0 = 0; k0 < K; k0 += BK) {
        __syncthreads();
#pragma unroll
        for (int i = 0; i < 2; ++i) {
            const int ar = i * 64 + wave * 16;   // 16 rows per wave per instr
            __builtin_amdgcn_global_load_lds(
                GLOBAL_AS(Ag + (size_t)(row0 + ar + lrow) * K + k0 + lc8),
                LDS_AS(&Ah[ar * BK]), 16, 0, 0);
            __builtin_amdgcn_global_load_lds(
                GLOBAL_AS(Bg + (size_t)(col0 + ar + lrow) * K + k0 + lc8),
                LDS_AS(&Bh[ar * BK]), 16, 0, 0);
            if constexpr (SPLIT) {
                __builtin_amdgcn_global_load_lds(
                    GLOBAL_AS(Alg + (size_t)(row0 + ar + lrow) * K + k0 + lc8),
                    LDS_AS(&Al[ar * BK]), 16, 0, 0);
                __builtin_amdgcn_global_load_lds(
                    GLOBAL_AS(Blg + (size_t)(col0 + ar + lrow) * K + k0 + lc8),
                    LDS_AS(&Bl[ar * BK]), 16, 0, 0);
            }
        }
        __syncthreads();

        short8 af[4], bfr[4], afl[4], bfl[4];
#pragma unroll
        for (int t = 0; t < 4; ++t) {
            af[t]  = *(const short8*)&Ah[(wr * 64 + t * 16 + l16) * BK + quad * 8];
            bfr[t] = *(const short8*)&Bh[(wc * 64 + t * 16 + l16) * BK + quad * 8];
            if constexpr (SPLIT) {
                afl[t] = *(const short8*)&Al[(wr * 64 + t * 16 + l16) * BK + quad * 8];
                bfl[t] = *(const short8*)&Bl[(wc * 64 + t * 16 + l16) * BK + quad * 8];
            }
        }
#pragma unroll
        for (int i = 0; i < 4; ++i)
#pragma unroll
            for (int j = 0; j < 4; ++j) {
                acc[i][j] = __builtin_amdgcn_mfma_f32_16x16x32_bf16(af[i], bfr[j], acc[i][j], 0, 0, 0);
                if constexpr (SPLIT) {
                    acc[i][j] = __builtin_amdgcn_mfma_f32_16x16x32_bf16(af[i],  bfl[j], acc[i][j], 0, 0, 0);
                    acc[i][j] = __builtin_amdgcn_mfma_f32_16x16x32_bf16(afl[i], bfr[j], acc[i][j], 0, 0, 0);
                }
            }
    }

    // epilogue: C/D layout row=quad*4+r, col=l16
#pragma unroll
    for (int i = 0; i < 4; ++i) {
#pragma unroll
        for (int j = 0; j < 4; ++j) {
            const int colb = col0 + wc * 64 + j * 16 + l16;
            const float bv = bias[colb];
#pragma unroll
            for (int r = 0; r < 4; ++r) {
                const int row = row0 + wr * 64 + i * 16 + quad * 4 + r;
                const float val = acc[i][j][r] + bv;
                if constexpr (EPI == 0) {
                    C[(size_t)row * N + colb] = val;
                } else {
                    if (colb < 2048) {
                        unsigned short hb = f2bf_rne(val);
                        qh[(size_t)row * 2048 + colb] = hb;
                        ql[(size_t)row * 2048 + colb] = f2bf_rne(val - bfbits2f(hb));
                    } else {
                        vb[(size_t)row * 1024 + colb - 2048] = f2bf_rne(val);
                    }
                }
            }
        }
    }
}

// ---------------------------------------------------------------------------
// MFMA causal flash attention — now reads pre-split q/k hi/lo planes and
// bf16 v; writes bf16 res. Math identical to round 2 (fp32-accurate logits).
// ---------------------------------------------------------------------------
__global__ __launch_bounds__(256) void flash_attn_mfma(
    const ushort_t* __restrict__ qk_hi, const ushort_t* __restrict__ qk_lo,
    const ushort_t* __restrict__ v_bf,  ushort_t* __restrict__ res_bf)
{
    __shared__ __align__(16) unsigned short KsHi[64][72];
    __shared__ __align__(16) unsigned short KsLo[64][72];
    __shared__ __align__(16) unsigned short Vt[64][72];      // [d][key]
    __shared__ __align__(16) unsigned short Pb[4][16][72];   // per-wave P

    const int h    = blockIdx.y;
    const int qt   = gridDim.x - 1 - blockIdx.x;   // heaviest tiles first
    const int bq0  = qt * 64;
    const int tid  = threadIdx.x;
    const int wave = tid >> 6;
    const int lane = tid & 63;
    const int l16  = lane & 15;
    const int quad = lane >> 4;
    const int q0   = bq0 + wave * 16;

    // Q fragments from pre-split planes
    const size_t qoff = (size_t)(q0 + l16) * 2048 + h * HDIM + quad * 8;
    short8 qhi0 = *(const short8*)(qk_hi + qoff);
    short8 qhi1 = *(const short8*)(qk_hi + qoff + 32);
    short8 qlo0 = *(const short8*)(qk_lo + qoff);
    short8 qlo1 = *(const short8*)(qk_lo + qoff + 32);

    float4_t o[4];
    float m[4], l[4];
#pragma unroll
    for (int ct = 0; ct < 4; ++ct) o[ct] = (float4_t){0.f, 0.f, 0.f, 0.f};
#pragma unroll
    for (int r = 0; r < 4; ++r) { m[r] = -INFINITY; l[r] = 0.f; }

    for (int kb = 0; kb <= bq0 + 63; kb += 64) {
        __syncthreads();
#pragma unroll
        for (int p = 0; p < 2; ++p) {
            const int key = p * 32 + (tid >> 3);
            const int d8  = (tid & 7) * 8;
            const size_t ko = (size_t)(kb + key) * 2048 + 1024 + h * HDIM + d8;
            *(short8*)&KsHi[key][d8] = *(const short8*)(qk_hi + ko);
            *(short8*)&KsLo[key][d8] = *(const short8*)(qk_lo + ko);
            const ushort_t* vp = v_bf + (size_t)(kb + key) * 1024 + h * HDIM + d8;
#pragma unroll
            for (int j = 0; j < 8; ++j) Vt[d8 + j][key] = vp[j];
        }
        __syncthreads();

        if (kb > q0 + 15) continue;   // wave-uniform skip

        float4_t s[4];
#pragma unroll
        for (int t = 0; t < 4; ++t) {
            s[t] = (float4_t){0.f, 0.f, 0.f, 0.f};
            const int kr = t * 16 + l16;
            short8 bh0 = *(const short8*)&KsHi[kr][quad * 8];
            short8 bh1 = *(const short8*)&KsHi[kr][32 + quad * 8];
            short8 bl0 = *(const short8*)&KsLo[kr][quad * 8];
            short8 bl1 = *(const short8*)&KsLo[kr][32 + quad * 8];
            s[t] = __builtin_amdgcn_mfma_f32_16x16x32_bf16(qhi0, bh0, s[t], 0, 0, 0);
            s[t] = __builtin_amdgcn_mfma_f32_16x16x32_bf16(qhi1, bh1, s[t], 0, 0, 0);
            s[t] = __builtin_amdgcn_mfma_f32_16x16x32_bf16(qlo0, bh0, s[t], 0, 0, 0);
            s[t] = __builtin_amdgcn_mfma_f32_16x16x32_bf16(qlo1, bh1, s[t], 0, 0, 0);
            s[t] = __builtin_amdgcn_mfma_f32_16x16x32_bf16(qhi0, bl0, s[t], 0, 0, 0);
            s[t] = __builtin_amdgcn_mfma_f32_16x16x32_bf16(qhi1, bl1, s[t], 0, 0, 0);
        }

#pragma unroll
        for (int t = 0; t < 4; ++t) {
            const int c = kb + t * 16 + l16;
#pragma unroll
            for (int r = 0; r < 4; ++r) {
                const int row = q0 + quad * 4 + r;
                if (c > row) s[t][r] = -INFINITY;
            }
        }
#pragma unroll
        for (int r = 0; r < 4; ++r) {
            float mx = fmaxf(fmaxf(s[0][r], s[1][r]), fmaxf(s[2][r], s[3][r]));
#pragma unroll
            for (int off = 1; off < 16; off <<= 1)
                mx = fmaxf(mx, __shfl_xor(mx, off));
            float mnew  = fmaxf(m[r], mx);
            float alpha = __expf(m[r] - mnew);
            float rowsum = 0.f;
#pragma unroll
            for (int t = 0; t < 4; ++t) {
                float p = __expf(s[t][r] - mnew);
                rowsum += p;
                Pb[wave][quad * 4 + r][t * 16 + l16] = f2bf_rne(p);
            }
#pragma unroll
            for (int off = 1; off < 16; off <<= 1)
                rowsum += __shfl_xor(rowsum, off);
            l[r] = l[r] * alpha + rowsum;
            m[r] = mnew;
#pragma unroll
            for (int ct = 0; ct < 4; ++ct) o[ct][r] *= alpha;
        }

        short8 pa0 = *(const short8*)&Pb[wave][l16][quad * 8];
        short8 pa1 = *(const short8*)&Pb[wave][l16][32 + quad * 8];
#pragma unroll
        for (int ct = 0; ct < 4; ++ct) {
            const int dr = ct * 16 + l16;
            short8 vb0 = *(const short8*)&Vt[dr][quad * 8];
            short8 vb1 = *(const short8*)&Vt[dr][32 + quad * 8];
            o[ct] = __builtin_amdgcn_mfma_f32_16x16x32_bf16(pa0, vb0, o[ct], 0, 0, 0);
            o[ct] = __builtin_amdgcn_mfma_f32_16x16x32_bf16(pa1, vb1, o[ct], 0, 0, 0);
        }
    }

    float inv[4];
#pragma unroll
    for (int r = 0; r < 4; ++r) inv[r] = 1.0f / l[r];
#pragma unroll
    for (int ct = 0; ct < 4; ++ct) {
#pragma unroll
        for (int r = 0; r < 4; ++r) {
            const int row = q0 + quad * 4 + r;
            res_bf[(size_t)row * EMB + h * HDIM + ct * 16 + l16] =
                f2bf_rne(o[ct][r] * inv[r]);
        }
    }
}

// ---------------------------------------------------------------------------
// launch
// ---------------------------------------------------------------------------
extern "C" void kernel_launch(void* const* d_in, const int* in_sizes, int n_in,
                              void* d_out, int out_size, void* d_ws, size_t ws_size,
                              hipStream_t stream)
{
    const float* x    = (const float*)d_in[0];
    const float* Wqkv = (const float*)d_in[2];
    const float* bqkv = (const float*)d_in[3];
    const float* Wp   = (const float*)d_in[4];
    const float* bp   = (const float*)d_in[5];
    float* out = (float*)d_out;

    ushort_t* xhi = (ushort_t*)d_ws;                     // [4096,1024]
    ushort_t* xlo = xhi + (size_t)4096 * 1024;           // [4096,1024]
    ushort_t* WTh = xlo + (size_t)4096 * 1024;           // [3072,1024]
    ushort_t* WTl = WTh + (size_t)3072 * 1024;
    ushort_t* qkh = WTl + (size_t)3072 * 1024;           // [4096,2048]
    ushort_t* qkl = qkh + (size_t)4096 * 2048;
    ushort_t* vbf = qkl + (size_t)4096 * 2048;           // [4096,1024]
    ushort_t* resb = xhi;   // alias: x splits dead after QKV GEMM
    ushort_t* WpT  = xlo;   // alias

    dim3 blk(256);

    split_x<<<4096, blk, 0, stream>>>(x, xhi, xlo);
    transpose_split<true><<<dim3(3072 / 64, 1024 / 64), blk, 0, stream>>>(
        Wqkv, WTh, WTl, 1024, 3072);

    gemm_mfma<true, 1><<<dim3(3072 / 128, 4096 / 128), blk, 0, stream>>>(
        xhi, xlo, WTh, WTl, bqkv, nullptr, qkh, qkl, vbf, 4096, 3072, 1024);

    transpose_split<false><<<dim3(1024 / 64, 1024 / 64), blk, 0, stream>>>(
        Wp, WpT, nullptr, 1024, 1024);

    flash_attn_mfma<<<dim3(S_LEN / 64, NHEAD), blk, 0, stream>>>(qkh, qkl, vbf, resb);

    gemm_mfma<false, 0><<<dim3(1024 / 128, 4096 / 128), blk, 0, stream>>>(
        resb, resb, WpT, WpT, bp, out, nullptr, nullptr, nullptr, 4096, 1024, 1024);
}

// Round 4
// 455.920 us; speedup vs baseline: 6.5455x; 1.3242x over previous
//
#include <hip/hip_runtime.h>
#include <hip/hip_bf16.h>
#include <math.h>

#define S_LEN 4096
#define EMB   1024
#define NHEAD 16
#define HDIM  64

typedef __attribute__((ext_vector_type(8))) short short8;
typedef __attribute__((ext_vector_type(4))) short short4_t;
typedef __attribute__((ext_vector_type(4))) float float4_t;
typedef unsigned short ushort_t;

#define GLOBAL_AS(p) ((const __attribute__((address_space(1))) void*)(p))
#define LDS_AS(p)    ((__attribute__((address_space(3))) void*)(p))

__device__ __forceinline__ unsigned short f2bf_rne(float f) {
    union { float f; unsigned int u; } v; v.f = f;
    unsigned int u = v.u;
    return (unsigned short)((u + 0x7FFF + ((u >> 16) & 1)) >> 16);
}
__device__ __forceinline__ float bfbits2f(unsigned short b) {
    union { unsigned int u; float f; } v; v.u = ((unsigned int)b) << 16;
    return v.f;
}

// ---------------------------------------------------------------------------
// split fp32 -> bf16 hi/lo planes (row-major, same layout)
// ---------------------------------------------------------------------------
__global__ __launch_bounds__(256) void split_x(
    const float* __restrict__ in, ushort_t* __restrict__ oh, ushort_t* __restrict__ ol)
{
    const int i = blockIdx.x * 256 + threadIdx.x;
    const float4_t v = ((const float4_t*)in)[i];
    short4_t h, l;
#pragma unroll
    for (int j = 0; j < 4; ++j) {
        unsigned short hb = f2bf_rne(v[j]);
        h[j] = (short)hb;
        l[j] = (short)f2bf_rne(v[j] - bfbits2f(hb));
    }
    ((short4_t*)oh)[i] = h;
    ((short4_t*)ol)[i] = l;
}

// ---------------------------------------------------------------------------
// transpose fp32 [R,C] -> bf16 [C,R] (hi, and lo if SPLIT)
// ---------------------------------------------------------------------------
template<bool SPLIT>
__global__ __launch_bounds__(256) void transpose_split(
    const float* __restrict__ in, ushort_t* __restrict__ oh, ushort_t* __restrict__ ol,
    int R, int C)
{
    __shared__ float t[64][65];
    const int r0 = blockIdx.y * 64, c0 = blockIdx.x * 64;
    for (int i = threadIdx.x; i < 64 * 64; i += 256) {
        int r = i >> 6, c = i & 63;
        t[r][c] = in[(size_t)(r0 + r) * C + c0 + c];
    }
    __syncthreads();
    for (int i = threadIdx.x; i < 64 * 64; i += 256) {
        int c = i >> 6, r = i & 63;
        float f = t[r][c];
        unsigned short hb = f2bf_rne(f);
        oh[(size_t)(c0 + c) * R + r0 + r] = hb;
        if constexpr (SPLIT)
            ol[(size_t)(c0 + c) * R + r0 + r] = f2bf_rne(f - bfbits2f(hb));
    }
}

// ---------------------------------------------------------------------------
// MFMA GEMM, m97 structure: 128x128 tile, BK=32, global_load_lds width 16.
// A [M,K] row-major bf16 (hi + optional lo); B^T [N,K] row-major bf16.
// SPLIT: acc = Ahi*Bhi + Ahi*Blo + Alo*Bhi (fp32-accurate product).
// EPI 0: C fp32 = acc + bias.   EPI 1 (QKV): cols<2048 -> qk hi/lo planes
// [4096,2048]; cols>=2048 -> V^T bf16 [1024,4096] (vt[(col-2048)*4096+row]).
// ---------------------------------------------------------------------------
template<bool SPLIT, int EPI>
__global__ __launch_bounds__(256) void gemm_mfma(
    const ushort_t* __restrict__ Ag, const ushort_t* __restrict__ Alg,
    const ushort_t* __restrict__ Bg, const ushort_t* __restrict__ Blg,
    const float* __restrict__ bias,
    float* __restrict__ C,
    ushort_t* __restrict__ qh, ushort_t* __restrict__ ql, ushort_t* __restrict__ vt,
    int M, int N, int K)
{
    constexpr int BK = 32;
    __shared__ ushort_t Ah[128 * BK];
    __shared__ ushort_t Bh[128 * BK];
    __shared__ ushort_t Al[SPLIT ? 128 * BK : 8];
    __shared__ ushort_t Bl[SPLIT ? 128 * BK : 8];

    const int tid = threadIdx.x;
    const int wave = tid >> 6, lane = tid & 63;
    const int l16 = lane & 15, quad = lane >> 4;
    const int wr = wave >> 1, wc = wave & 1;
    const int row0 = blockIdx.y * 128, col0 = blockIdx.x * 128;
    const int lrow = lane >> 2, lc8 = (lane & 3) * 8;

    float4_t acc[4][4];
#pragma unroll
    for (int i = 0; i < 4; ++i)
#pragma unroll
        for (int j = 0; j < 4; ++j) acc[i][j] = (float4_t){0.f, 0.f, 0.f, 0.f};

    for (int k0 = 0; k0 < K; k0 += BK) {
        __syncthreads();
#pragma unroll
        for (int i = 0; i < 2; ++i) {
            const int ar = i * 64 + wave * 16;
            __builtin_amdgcn_global_load_lds(
                GLOBAL_AS(Ag + (size_t)(row0 + ar + lrow) * K + k0 + lc8),
                LDS_AS(&Ah[ar * BK]), 16, 0, 0);
            __builtin_amdgcn_global_load_lds(
                GLOBAL_AS(Bg + (size_t)(col0 + ar + lrow) * K + k0 + lc8),
                LDS_AS(&Bh[ar * BK]), 16, 0, 0);
            if constexpr (SPLIT) {
                __builtin_amdgcn_global_load_lds(
                    GLOBAL_AS(Alg + (size_t)(row0 + ar + lrow) * K + k0 + lc8),
                    LDS_AS(&Al[ar * BK]), 16, 0, 0);
                __builtin_amdgcn_global_load_lds(
                    GLOBAL_AS(Blg + (size_t)(col0 + ar + lrow) * K + k0 + lc8),
                    LDS_AS(&Bl[ar * BK]), 16, 0, 0);
            }
        }
        __syncthreads();

        short8 af[4], bfr[4], afl[4], bfl[4];
#pragma unroll
        for (int t = 0; t < 4; ++t) {
            af[t]  = *(const short8*)&Ah[(wr * 64 + t * 16 + l16) * BK + quad * 8];
            bfr[t] = *(const short8*)&Bh[(wc * 64 + t * 16 + l16) * BK + quad * 8];
            if constexpr (SPLIT) {
                afl[t] = *(const short8*)&Al[(wr * 64 + t * 16 + l16) * BK + quad * 8];
                bfl[t] = *(const short8*)&Bl[(wc * 64 + t * 16 + l16) * BK + quad * 8];
            }
        }
#pragma unroll
        for (int i = 0; i < 4; ++i)
#pragma unroll
            for (int j = 0; j < 4; ++j) {
                acc[i][j] = __builtin_amdgcn_mfma_f32_16x16x32_bf16(af[i], bfr[j], acc[i][j], 0, 0, 0);
                if constexpr (SPLIT) {
                    acc[i][j] = __builtin_amdgcn_mfma_f32_16x16x32_bf16(af[i],  bfl[j], acc[i][j], 0, 0, 0);
                    acc[i][j] = __builtin_amdgcn_mfma_f32_16x16x32_bf16(afl[i], bfr[j], acc[i][j], 0, 0, 0);
                }
            }
    }

    // epilogue: C/D layout row=quad*4+r, col=l16
#pragma unroll
    for (int i = 0; i < 4; ++i) {
#pragma unroll
        for (int j = 0; j < 4; ++j) {
            const int colb = col0 + wc * 64 + j * 16 + l16;
            const float bv = bias[colb];
#pragma unroll
            for (int r = 0; r < 4; ++r) {
                const int row = row0 + wr * 64 + i * 16 + quad * 4 + r;
                const float val = acc[i][j][r] + bv;
                if constexpr (EPI == 0) {
                    C[(size_t)row * N + colb] = val;
                } else {
                    if (colb < 2048) {
                        unsigned short hb = f2bf_rne(val);
                        qh[(size_t)row * 2048 + colb] = hb;
                        ql[(size_t)row * 2048 + colb] = f2bf_rne(val - bfbits2f(hb));
                    } else {
                        // V^T: [d_global][s] — consecutive r -> contiguous
                        vt[(size_t)(colb - 2048) * 4096 + row] = f2bf_rne(val);
                    }
                }
            }
        }
    }
}

// ---------------------------------------------------------------------------
// MFMA causal flash attention, balanced + low-LDS-traffic version.
// Grid (32, 16): block handles q-tiles {bx, 63-bx} of head by -> uniform
// 65 k-iterations. Block = 128 threads = 2 waves; wave covers 32 q-rows as
// two 16-row m-groups sharing each K/V fragment read. V^T comes pre-
// transposed from global (no LDS scatter). Next tile prefetched to regs.
// ---------------------------------------------------------------------------
__global__ __launch_bounds__(128) void flash_attn_mfma(
    const ushort_t* __restrict__ qk_hi, const ushort_t* __restrict__ qk_lo,
    const ushort_t* __restrict__ v_t,  ushort_t* __restrict__ res_bf)
{
    __shared__ __align__(16) ushort_t KsHi[64][72];
    __shared__ __align__(16) ushort_t KsLo[64][72];
    __shared__ __align__(16) ushort_t Vt[64][72];        // V^T tile [d][key]
    __shared__ __align__(16) ushort_t Pb[2][2][16][72];  // [wave][grp][row][col]

    const int h    = blockIdx.y;
    const int tid  = threadIdx.x;
    const int wave = tid >> 6;
    const int lane = tid & 63;
    const int l16  = lane & 15;
    const int quad = lane >> 4;
    const int srow = tid >> 3;          // 0..15
    const int sc8  = (tid & 7) * 8;     // 0..56

    for (int half = 0; half < 2; ++half) {
        const int tile = half ? 63 - (int)blockIdx.x : (int)blockIdx.x;
        const int bq0  = tile * 64;
        const int q0   = bq0 + wave * 32;

        // Q fragments for both 16-row groups
        short8 qhi[2][2], qlo[2][2];
#pragma unroll
        for (int g = 0; g < 2; ++g) {
            const size_t qoff = (size_t)(q0 + g * 16 + l16) * 2048 + h * HDIM + quad * 8;
            qhi[g][0] = *(const short8*)(qk_hi + qoff);
            qhi[g][1] = *(const short8*)(qk_hi + qoff + 32);
            qlo[g][0] = *(const short8*)(qk_lo + qoff);
            qlo[g][1] = *(const short8*)(qk_lo + qoff + 32);
        }

        float4_t o[2][4];
        float m[2][4], l[2][4];
#pragma unroll
        for (int g = 0; g < 2; ++g)
#pragma unroll
            for (int c = 0; c < 4; ++c) {
                o[g][c] = (float4_t){0.f, 0.f, 0.f, 0.f};
                m[g][c] = -INFINITY; l[g][c] = 0.f;
            }

        // register prefetch buffers (4 rows per plane per thread)
        short8 pf_kh[4], pf_kl[4], pf_v[4];
#pragma unroll
        for (int p = 0; p < 4; ++p) {
            const int r = srow + p * 16;
            pf_kh[p] = *(const short8*)(qk_hi + (size_t)r * 2048 + 1024 + h * HDIM + sc8);
            pf_kl[p] = *(const short8*)(qk_lo + (size_t)r * 2048 + 1024 + h * HDIM + sc8);
            pf_v[p]  = *(const short8*)(v_t  + (size_t)(h * HDIM + r) * 4096 + 0 + sc8);
        }

        for (int kb = 0; kb <= bq0; kb += 64) {
            __syncthreads();   // previous iteration's readers done
#pragma unroll
            for (int p = 0; p < 4; ++p) {
                const int r = srow + p * 16;
                *(short8*)&KsHi[r][sc8] = pf_kh[p];
                *(short8*)&KsLo[r][sc8] = pf_kl[p];
                *(short8*)&Vt[r][sc8]   = pf_v[p];
            }
            __syncthreads();   // tile visible to all waves

            if (kb < bq0) {    // prefetch next tile (overlaps compute)
                const int kn = kb + 64;
#pragma unroll
                for (int p = 0; p < 4; ++p) {
                    const int r = srow + p * 16;
                    pf_kh[p] = *(const short8*)(qk_hi + (size_t)(kn + r) * 2048 + 1024 + h * HDIM + sc8);
                    pf_kl[p] = *(const short8*)(qk_lo + (size_t)(kn + r) * 2048 + 1024 + h * HDIM + sc8);
                    pf_v[p]  = *(const short8*)(v_t  + (size_t)(h * HDIM + r) * 4096 + kn + sc8);
                }
            }

            // ---- S = Q K^T for both groups, shared B-fragment reads --------
            float4_t s[2][4];
#pragma unroll
            for (int t = 0; t < 4; ++t) {
                const int kr = t * 16 + l16;
                short8 bh0 = *(const short8*)&KsHi[kr][quad * 8];
                short8 bh1 = *(const short8*)&KsHi[kr][32 + quad * 8];
                short8 bl0 = *(const short8*)&KsLo[kr][quad * 8];
                short8 bl1 = *(const short8*)&KsLo[kr][32 + quad * 8];
#pragma unroll
                for (int g = 0; g < 2; ++g) {
                    float4_t a = (float4_t){0.f, 0.f, 0.f, 0.f};
                    a = __builtin_amdgcn_mfma_f32_16x16x32_bf16(qhi[g][0], bh0, a, 0, 0, 0);
                    a = __builtin_amdgcn_mfma_f32_16x16x32_bf16(qhi[g][1], bh1, a, 0, 0, 0);
                    a = __builtin_amdgcn_mfma_f32_16x16x32_bf16(qlo[g][0], bh0, a, 0, 0, 0);
                    a = __builtin_amdgcn_mfma_f32_16x16x32_bf16(qlo[g][1], bh1, a, 0, 0, 0);
                    a = __builtin_amdgcn_mfma_f32_16x16x32_bf16(qhi[g][0], bl0, a, 0, 0, 0);
                    a = __builtin_amdgcn_mfma_f32_16x16x32_bf16(qhi[g][1], bl1, a, 0, 0, 0);
                    s[g][t] = a;
                }
            }

            // ---- causal mask (only the diagonal tile needs it) -------------
            if (kb == bq0) {
#pragma unroll
                for (int t = 0; t < 4; ++t) {
                    const int c = kb + t * 16 + l16;
#pragma unroll
                    for (int g = 0; g < 2; ++g)
#pragma unroll
                        for (int r = 0; r < 4; ++r) {
                            const int row = q0 + g * 16 + quad * 4 + r;
                            if (c > row) s[g][t][r] = -INFINITY;
                        }
                }
            }

            // ---- online softmax -------------------------------------------
#pragma unroll
            for (int g = 0; g < 2; ++g)
#pragma unroll
                for (int r = 0; r < 4; ++r) {
                    float mx = fmaxf(fmaxf(s[g][0][r], s[g][1][r]),
                                     fmaxf(s[g][2][r], s[g][3][r]));
#pragma unroll
                    for (int off = 1; off < 16; off <<= 1)
                        mx = fmaxf(mx, __shfl_xor(mx, off));
                    float mnew  = fmaxf(m[g][r], mx);
                    float alpha = __expf(m[g][r] - mnew);
                    float rowsum = 0.f;
#pragma unroll
                    for (int t = 0; t < 4; ++t) {
                        float p = __expf(s[g][t][r] - mnew);
                        rowsum += p;
                        Pb[wave][g][quad * 4 + r][t * 16 + l16] = f2bf_rne(p);
                    }
#pragma unroll
                    for (int off = 1; off < 16; off <<= 1)
                        rowsum += __shfl_xor(rowsum, off);
                    l[g][r] = l[g][r] * alpha + rowsum;
                    m[g][r] = mnew;
#pragma unroll
                    for (int ct = 0; ct < 4; ++ct) o[g][ct][r] *= alpha;
                }

            // ---- O += P V, shared V-fragment reads -------------------------
            short8 pa[2][2];
#pragma unroll
            for (int g = 0; g < 2; ++g) {
                pa[g][0] = *(const short8*)&Pb[wave][g][l16][quad * 8];
                pa[g][1] = *(const short8*)&Pb[wave][g][l16][32 + quad * 8];
            }
#pragma unroll
            for (int ct = 0; ct < 4; ++ct) {
                const int dr = ct * 16 + l16;
                short8 vb0 = *(const short8*)&Vt[dr][quad * 8];
                short8 vb1 = *(const short8*)&Vt[dr][32 + quad * 8];
#pragma unroll
                for (int g = 0; g < 2; ++g) {
                    o[g][ct] = __builtin_amdgcn_mfma_f32_16x16x32_bf16(pa[g][0], vb0, o[g][ct], 0, 0, 0);
                    o[g][ct] = __builtin_amdgcn_mfma_f32_16x16x32_bf16(pa[g][1], vb1, o[g][ct], 0, 0, 0);
                }
            }
        } // kb

        // ---- epilogue ------------------------------------------------------
#pragma unroll
        for (int g = 0; g < 2; ++g) {
            float inv[4];
#pragma unroll
            for (int r = 0; r < 4; ++r) inv[r] = 1.0f / l[g][r];
#pragma unroll
            for (int ct = 0; ct < 4; ++ct)
#pragma unroll
                for (int r = 0; r < 4; ++r) {
                    const int row = q0 + g * 16 + quad * 4 + r;
                    res_bf[(size_t)row * EMB + h * HDIM + ct * 16 + l16] =
                        f2bf_rne(o[g][ct][r] * inv[r]);
                }
        }
    } // half
}

// ---------------------------------------------------------------------------
// launch
// ---------------------------------------------------------------------------
extern "C" void kernel_launch(void* const* d_in, const int* in_sizes, int n_in,
                              void* d_out, int out_size, void* d_ws, size_t ws_size,
                              hipStream_t stream)
{
    const float* x    = (const float*)d_in[0];
    const float* Wqkv = (const float*)d_in[2];
    const float* bqkv = (const float*)d_in[3];
    const float* Wp   = (const float*)d_in[4];
    const float* bp   = (const float*)d_in[5];
    float* out = (float*)d_out;

    ushort_t* xhi = (ushort_t*)d_ws;                     // [4096,1024]
    ushort_t* xlo = xhi + (size_t)4096 * 1024;           // [4096,1024]
    ushort_t* WTh = xlo + (size_t)4096 * 1024;           // [3072,1024]
    ushort_t* WTl = WTh + (size_t)3072 * 1024;
    ushort_t* qkh = WTl + (size_t)3072 * 1024;           // [4096,2048]
    ushort_t* qkl = qkh + (size_t)4096 * 2048;
    ushort_t* vtg = qkl + (size_t)4096 * 2048;           // V^T [1024,4096]
    ushort_t* resb = xhi;   // alias: x splits dead after QKV GEMM
    ushort_t* WpT  = xlo;   // alias

    dim3 blk(256);

    split_x<<<4096, blk, 0, stream>>>(x, xhi, xlo);
    transpose_split<true><<<dim3(3072 / 64, 1024 / 64), blk, 0, stream>>>(
        Wqkv, WTh, WTl, 1024, 3072);

    gemm_mfma<true, 1><<<dim3(3072 / 128, 4096 / 128), blk, 0, stream>>>(
        xhi, xlo, WTh, WTl, bqkv, nullptr, qkh, qkl, vtg, 4096, 3072, 1024);

    transpose_split<false><<<dim3(1024 / 64, 1024 / 64), blk, 0, stream>>>(
        Wp, WpT, nullptr, 1024, 1024);

    flash_attn_mfma<<<dim3(32, NHEAD), dim3(128), 0, stream>>>(qkh, qkl, vtg, resb);

    gemm_mfma<false, 0><<<dim3(1024 / 128, 4096 / 128), blk, 0, stream>>>(
        resb, resb, WpT, WpT, bp, out, nullptr, nullptr, nullptr, 4096, 1024, 1024);
}